// Round 6
// baseline (160.175 us; speedup 1.0000x reference)
//
#include <hip/hip_runtime.h>
#include <hip/hip_bf16.h>

typedef __attribute__((ext_vector_type(8))) short short8;
typedef __attribute__((ext_vector_type(16))) float f32x16;

__device__ __forceinline__ unsigned short bfbits(float f) {
  return __builtin_bit_cast(unsigned short, __float2bfloat16(f));
}

__device__ __forceinline__ short8 lds_read16(const short* p, int byteOff) {
  return *reinterpret_cast<const short8*>(reinterpret_cast<const char*>(p) + byteOff);
}

#define MFMA(a, b, c) __builtin_amdgcn_mfma_f32_32x32x16_bf16((a), (b), (c), 0, 0, 0)

// x:[524288][64] f32 (flat reinterpret of [B,E,S,D]; expert = row>>16)
// w1:[8][64][256] f32, w2:[8][256][64] f32, out same shape as x.
// Grid 1024 x 256 threads. expert = blockIdx&7 (XCD-pinned), chunk =
// blockIdx>>3 owns 512 rows; 4 waves x 4 tiles x 32 rows.
//
// Register story (R2-R5 measured): body needs ~150-175 live VGPRs. The
// allocator's default heuristic targets the LDS-allowed occupancy (4
// waves/EU -> 128 VGPR) and SPILLS the rest (~70-140 MB HBM scratch tax;
// launch_bounds can only lower the target). waves_per_eu(2,2) sets the
// target to 2 waves/EU -> 256-VGPR budget -> zero spill. Measured
// occupancy was ~7 waves/CU anyway, so the max=2 cap (8 waves/CU via
// 2x256-thread blocks) costs nothing.
__launch_bounds__(256)
__attribute__((amdgpu_waves_per_eu(2, 2)))
__global__ void ffn_fused(const float* __restrict__ x,
                          const float* __restrict__ w1,
                          const float* __restrict__ w2,
                          float* __restrict__ out) {
  // W1^T: [f=256][d=64] bf16, row pitch 128 B, byte ^= (f&7)<<4
  // W2^T: [d=64][f=256] bf16, row pitch 512 B, byte ^= (d&31)<<4
  __shared__ short w1t[256 * 64];
  __shared__ short w2t[64 * 256];

  const int tid  = threadIdx.x;
  const int lane = tid & 63;
  const int wv   = tid >> 6;   // wave 0..3
  const int m    = lane & 31;
  const int g    = lane >> 5;

  const int e     = blockIdx.x & 7;   // expert -> XCD pinned (128 KB weights/XCD-L2)
  const int chunk = blockIdx.x >> 3;  // 0..127

  const float* W1 = w1 + e * (64 * 256);
  const float* W2 = w2 + e * (256 * 64);

  const long rowBase = (long)e * 65536 + (long)chunk * 512 + wv * 128;

  // ---- issue it=0 x loads FIRST: latency hides under weight staging ----
  float4 raw[8];
#pragma unroll
  for (int ks = 0; ks < 4; ++ks) {
    const float* px = x + (rowBase + m) * 64 + ks * 16 + g * 8;
    raw[2 * ks]     = *reinterpret_cast<const float4*>(px);
    raw[2 * ks + 1] = *reinterpret_cast<const float4*>(px + 4);
  }

  // ---- stage W1^T (thread t owns column f=t; 16 d-quads) ----
  {
    const int f   = tid;
    const int swz = (f & 7) << 4;
#pragma unroll
    for (int i = 0; i < 16; ++i) {
      float a0 = W1[(4 * i + 0) * 256 + f];
      float a1 = W1[(4 * i + 1) * 256 + f];
      float a2 = W1[(4 * i + 2) * 256 + f];
      float a3 = W1[(4 * i + 3) * 256 + f];
      unsigned lo = (unsigned)bfbits(a0) | ((unsigned)bfbits(a1) << 16);
      unsigned hi = (unsigned)bfbits(a2) | ((unsigned)bfbits(a3) << 16);
      const int off = (f * 128 + i * 8) ^ swz;
      *reinterpret_cast<uint2*>(reinterpret_cast<char*>(w1t) + off) = make_uint2(lo, hi);
    }
  }
  // ---- stage W2^T (thread t owns column d=t&63; 16 f-quads) ----
  {
    const int d   = tid & 63;
    const int fb  = tid >> 6;  // 0..3
    const int swz = (d & 31) << 4;
#pragma unroll
    for (int i = 0; i < 16; ++i) {
      const int f4 = fb + 4 * i;
      const int f  = 4 * f4;
      float a0 = W2[(f + 0) * 64 + d];
      float a1 = W2[(f + 1) * 64 + d];
      float a2 = W2[(f + 2) * 64 + d];
      float a3 = W2[(f + 3) * 64 + d];
      unsigned lo = (unsigned)bfbits(a0) | ((unsigned)bfbits(a1) << 16);
      unsigned hi = (unsigned)bfbits(a2) | ((unsigned)bfbits(a3) << 16);
      const int off = (d * 512 + f4 * 8) ^ swz;
      *reinterpret_cast<uint2*>(reinterpret_cast<char*>(w2t) + off) = make_uint2(lo, hi);
    }
  }
  __syncthreads();  // only barrier in the kernel

  const int swzm = (m & 7) << 4;
  const int swzd = m << 4;  // ((d&31)<<4, d = m and 32+m give same value)

  for (int it = 0; it < 4; ++it) {
    const long rb = rowBase + it * 32;  // this wave's 32 rows this tile

    // ---- convert raw -> bf16 fragments (B-op of GEMM1: x^T) ----
    short8 xf[4];
#pragma unroll
    for (int ks = 0; ks < 4; ++ks) {
      const float4 u0 = raw[2 * ks];
      const float4 u1 = raw[2 * ks + 1];
      short8 v;
      v[0] = (short)bfbits(u0.x); v[1] = (short)bfbits(u0.y);
      v[2] = (short)bfbits(u0.z); v[3] = (short)bfbits(u0.w);
      v[4] = (short)bfbits(u1.x); v[5] = (short)bfbits(u1.y);
      v[6] = (short)bfbits(u1.z); v[7] = (short)bfbits(u1.w);
      xf[ks] = v;
    }

    // ---- software pipeline: issue next it's x loads now; they complete
    //      under the ft-loop's ~1000 cy of MFMA+VALU work ----
    if (it < 3) {
      const long rbn = rb + 32;
#pragma unroll
      for (int ks = 0; ks < 4; ++ks) {
        const float* px = x + (rbn + m) * 64 + ks * 16 + g * 8;
        raw[2 * ks]     = *reinterpret_cast<const float4*>(px);
        raw[2 * ks + 1] = *reinterpret_cast<const float4*>(px + 4);
      }
    }

    f32x16 o0, o1;  // out^T acc per dt half
#pragma unroll
    for (int i = 0; i < 16; ++i) { o0[i] = 0.f; o1[i] = 0.f; }

#pragma unroll
    for (int ft = 0; ft < 8; ++ft) {
      // GEMM1: h^T tile [32f x 32m] = W1^T frag x x^T frag, K=64 (4 steps)
      short8 a[4];
#pragma unroll
      for (int ks = 0; ks < 4; ++ks)
        a[ks] = lds_read16(w1t, ((ft * 32 + m) * 128 + ks * 32 + g * 16) ^ swzm);

      f32x16 h;
#pragma unroll
      for (int i = 0; i < 16; ++i) h[i] = 0.f;
#pragma unroll
      for (int ks = 0; ks < 4; ++ks) h = MFMA(a[ks], xf[ks], h);

      // relu + pack to bf16 pairs: pk[2q+hh] covers C regs 4q..4q+3
      unsigned pk[8];
#pragma unroll
      for (int q = 0; q < 4; ++q) {
        pk[2*q]   = (unsigned)bfbits(fmaxf(h[4*q+0], 0.f)) | ((unsigned)bfbits(fmaxf(h[4*q+1], 0.f)) << 16);
        pk[2*q+1] = (unsigned)bfbits(fmaxf(h[4*q+2], 0.f)) | ((unsigned)bfbits(fmaxf(h[4*q+3], 0.f)) << 16);
      }

      // GEMM2: out^T += W2^T frag x h^T frag; h^T B-frag built in-register
      // via one cross-half __shfl_xor(32) pair per fragment (PROVEN R1/R3).
#pragma unroll
      for (int sub = 0; sub < 2; ++sub) {
        const int ks2 = 2 * ft + sub;
        const short8 wA = lds_read16(w2t, (m * 512 + ks2 * 32 + g * 16) ^ swzd);
        const short8 wB = lds_read16(w2t, ((32 + m) * 512 + ks2 * 32 + g * 16) ^ swzd);
        const int qa = 2 * sub, qb = 2 * sub + 1;

        union { short8 v; unsigned u[4]; } b;
        {
          unsigned pa0 = pk[2*qa], pa1 = pk[2*qa+1];
          unsigned pb0 = pk[2*qb], pb1 = pk[2*qb+1];
          unsigned s0 = g ? pa0 : pb0, s1 = g ? pa1 : pb1;  // what partner needs
          unsigned k0 = g ? pb0 : pa0, k1 = g ? pb1 : pa1;  // what I keep
          unsigned r0 = __shfl_xor(s0, 32, 64);
          unsigned r1 = __shfl_xor(s1, 32, 64);
          b.u[0] = g ? r0 : k0; b.u[1] = g ? r1 : k1;
          b.u[2] = g ? k0 : r0; b.u[3] = g ? k1 : r1;
        }

        o0 = MFMA(wA, b.v, o0);
        o1 = MFMA(wB, b.v, o1);
      }
    }

    // ---- store out^T C-frags: 4 consecutive d per reg-quad -> float4 stores ----
#pragma unroll
    for (int dt = 0; dt < 2; ++dt) {
      const f32x16& acc = dt == 0 ? o0 : o1;
      float* po = out + (rb + m) * 64 + dt * 32 + g * 4;
#pragma unroll
      for (int q = 0; q < 4; ++q) {
        float4 s;
        s.x = acc[4*q+0]; s.y = acc[4*q+1]; s.z = acc[4*q+2]; s.w = acc[4*q+3];
        *reinterpret_cast<float4*>(po + 8 * q) = s;  // d = dt*32 + 8q + 4g + 0..3
      }
    }
  }
}

extern "C" void kernel_launch(void* const* d_in, const int* in_sizes, int n_in,
                              void* d_out, int out_size, void* d_ws, size_t ws_size,
                              hipStream_t stream) {
  const float* x  = (const float*)d_in[0];
  const float* w1 = (const float*)d_in[1];
  const float* w2 = (const float*)d_in[2];
  float* out = (float*)d_out;
  ffn_fused<<<dim3(1024), dim3(256), 0, stream>>>(x, w1, w2, out);
}

// Round 7
// 86.684 us; speedup vs baseline: 1.8478x; 1.8478x over previous
//
#include <hip/hip_runtime.h>
#include <hip/hip_bf16.h>

typedef __attribute__((ext_vector_type(8))) short short8;
typedef __attribute__((ext_vector_type(16))) float f32x16;

__device__ __forceinline__ unsigned short bfbits(float f) {
  return __builtin_bit_cast(unsigned short, __float2bfloat16(f));
}

__device__ __forceinline__ short8 lds_read16(const short* p, int byteOff) {
  return *reinterpret_cast<const short8*>(reinterpret_cast<const char*>(p) + byteOff);
}

#define MFMA(a, b, c) __builtin_amdgcn_mfma_f32_32x32x16_bf16((a), (b), (c), 0, 0, 0)

// x:[524288][64] f32 (flat reinterpret of [B,E,S,D]; expert = row>>16)
// w1:[8][64][256] f32, w2:[8][256][64] f32, out same shape as x.
// Grid 512 x 256 threads. expert = blockIdx&7 (XCD-pinned), chunk =
// blockIdx>>3 owns 1024 rows; 4 waves x 8 tiles x 32 rows (256 rows/wave --
// scratch tax is ~fixed per THREAD, so fewer threads + more rows/thread wins;
// R1 vs R3/R6 measured).
//
// Spill story (R1-R6 measured): excess HBM traffic ~80-145 dwords/thread,
// independent of tile count => one-shot code, i.e. the fully-unrolled weight
// staging (16x4 hoisted global loads held live). unroll 2 bounds in-flight
// staging loads to ~8 dwords -> no spill. launch_bounds 2nd arg and
// amdgpu_waves_per_eu cannot RAISE the 128-VGPR allocator target (R2/R3/R6).
__launch_bounds__(256)
__global__ void ffn_fused(const float* __restrict__ x,
                          const float* __restrict__ w1,
                          const float* __restrict__ w2,
                          float* __restrict__ out) {
  // W1^T: [f=256][d=64] bf16, row pitch 128 B, byte ^= (f&7)<<4
  // W2^T: [d=64][f=256] bf16, row pitch 512 B, byte ^= (d&31)<<4
  __shared__ short w1t[256 * 64];
  __shared__ short w2t[64 * 256];

  const int tid  = threadIdx.x;
  const int lane = tid & 63;
  const int wv   = tid >> 6;   // wave 0..3
  const int m    = lane & 31;
  const int g    = lane >> 5;

  const int e     = blockIdx.x & 7;   // expert -> XCD pinned (128 KB weights/XCD-L2)
  const int chunk = blockIdx.x >> 3;  // 0..63

  const float* W1 = w1 + e * (64 * 256);
  const float* W2 = w2 + e * (256 * 64);

  const long rowBase = (long)e * 65536 + (long)chunk * 1024 + wv * 256;

  // ---- issue it=0 x loads FIRST: latency hides under weight staging ----
  float4 raw[8];
#pragma unroll
  for (int ks = 0; ks < 4; ++ks) {
    const float* px = x + (rowBase + m) * 64 + ks * 16 + g * 8;
    raw[2 * ks]     = *reinterpret_cast<const float4*>(px);
    raw[2 * ks + 1] = *reinterpret_cast<const float4*>(px + 4);
  }

  // ---- stage W1^T (thread t owns column f=t; 16 d-quads) ----
  // unroll 2: bound in-flight staging loads (full unroll spilled ~64 dw/thread)
  {
    const int f   = tid;
    const int swz = (f & 7) << 4;
#pragma unroll 2
    for (int i = 0; i < 16; ++i) {
      float a0 = W1[(4 * i + 0) * 256 + f];
      float a1 = W1[(4 * i + 1) * 256 + f];
      float a2 = W1[(4 * i + 2) * 256 + f];
      float a3 = W1[(4 * i + 3) * 256 + f];
      unsigned lo = (unsigned)bfbits(a0) | ((unsigned)bfbits(a1) << 16);
      unsigned hi = (unsigned)bfbits(a2) | ((unsigned)bfbits(a3) << 16);
      const int off = (f * 128 + i * 8) ^ swz;
      *reinterpret_cast<uint2*>(reinterpret_cast<char*>(w1t) + off) = make_uint2(lo, hi);
    }
  }
  // ---- stage W2^T (thread t owns column d=t&63; 16 f-quads) ----
  {
    const int d   = tid & 63;
    const int fb  = tid >> 6;  // 0..3
    const int swz = (d & 31) << 4;
#pragma unroll 2
    for (int i = 0; i < 16; ++i) {
      const int f4 = fb + 4 * i;
      const int f  = 4 * f4;
      float a0 = W2[(f + 0) * 64 + d];
      float a1 = W2[(f + 1) * 64 + d];
      float a2 = W2[(f + 2) * 64 + d];
      float a3 = W2[(f + 3) * 64 + d];
      unsigned lo = (unsigned)bfbits(a0) | ((unsigned)bfbits(a1) << 16);
      unsigned hi = (unsigned)bfbits(a2) | ((unsigned)bfbits(a3) << 16);
      const int off = (d * 512 + f4 * 8) ^ swz;
      *reinterpret_cast<uint2*>(reinterpret_cast<char*>(w2t) + off) = make_uint2(lo, hi);
    }
  }
  __syncthreads();  // only barrier in the kernel

  const int swzm = (m & 7) << 4;
  const int swzd = m << 4;  // ((d&31)<<4, d = m and 32+m give same value)

  for (int it = 0; it < 8; ++it) {
    const long rb = rowBase + it * 32;  // this wave's 32 rows this tile

    // ---- convert raw -> bf16 fragments (B-op of GEMM1: x^T) ----
    short8 xf[4];
#pragma unroll
    for (int ks = 0; ks < 4; ++ks) {
      const float4 u0 = raw[2 * ks];
      const float4 u1 = raw[2 * ks + 1];
      short8 v;
      v[0] = (short)bfbits(u0.x); v[1] = (short)bfbits(u0.y);
      v[2] = (short)bfbits(u0.z); v[3] = (short)bfbits(u0.w);
      v[4] = (short)bfbits(u1.x); v[5] = (short)bfbits(u1.y);
      v[6] = (short)bfbits(u1.z); v[7] = (short)bfbits(u1.w);
      xf[ks] = v;
    }

    // ---- software pipeline: issue next tile's x loads now; they complete
    //      under the ft-loop's MFMA+VALU work ----
    if (it < 7) {
      const long rbn = rb + 32;
#pragma unroll
      for (int ks = 0; ks < 4; ++ks) {
        const float* px = x + (rbn + m) * 64 + ks * 16 + g * 8;
        raw[2 * ks]     = *reinterpret_cast<const float4*>(px);
        raw[2 * ks + 1] = *reinterpret_cast<const float4*>(px + 4);
      }
    }

    f32x16 o0, o1;  // out^T acc per dt half
#pragma unroll
    for (int i = 0; i < 16; ++i) { o0[i] = 0.f; o1[i] = 0.f; }

#pragma unroll
    for (int ft = 0; ft < 8; ++ft) {
      // GEMM1: h^T tile [32f x 32m] = W1^T frag x x^T frag, K=64 (4 steps)
      short8 a[4];
#pragma unroll
      for (int ks = 0; ks < 4; ++ks)
        a[ks] = lds_read16(w1t, ((ft * 32 + m) * 128 + ks * 32 + g * 16) ^ swzm);

      f32x16 h;
#pragma unroll
      for (int i = 0; i < 16; ++i) h[i] = 0.f;
#pragma unroll
      for (int ks = 0; ks < 4; ++ks) h = MFMA(a[ks], xf[ks], h);

      // relu + pack to bf16 pairs: pk[2q+hh] covers C regs 4q..4q+3
      unsigned pk[8];
#pragma unroll
      for (int q = 0; q < 4; ++q) {
        pk[2*q]   = (unsigned)bfbits(fmaxf(h[4*q+0], 0.f)) | ((unsigned)bfbits(fmaxf(h[4*q+1], 0.f)) << 16);
        pk[2*q+1] = (unsigned)bfbits(fmaxf(h[4*q+2], 0.f)) | ((unsigned)bfbits(fmaxf(h[4*q+3], 0.f)) << 16);
      }

      // GEMM2: out^T += W2^T frag x h^T frag; h^T B-frag built in-register
      // via one cross-half __shfl_xor(32) pair per fragment (PROVEN R1/R3).
#pragma unroll
      for (int sub = 0; sub < 2; ++sub) {
        const int ks2 = 2 * ft + sub;
        const short8 wA = lds_read16(w2t, (m * 512 + ks2 * 32 + g * 16) ^ swzd);
        const short8 wB = lds_read16(w2t, ((32 + m) * 512 + ks2 * 32 + g * 16) ^ swzd);
        const int qa = 2 * sub, qb = 2 * sub + 1;

        union { short8 v; unsigned u[4]; } b;
        {
          unsigned pa0 = pk[2*qa], pa1 = pk[2*qa+1];
          unsigned pb0 = pk[2*qb], pb1 = pk[2*qb+1];
          unsigned s0 = g ? pa0 : pb0, s1 = g ? pa1 : pb1;  // what partner needs
          unsigned k0 = g ? pb0 : pa0, k1 = g ? pb1 : pa1;  // what I keep
          unsigned r0 = __shfl_xor(s0, 32, 64);
          unsigned r1 = __shfl_xor(s1, 32, 64);
          b.u[0] = g ? r0 : k0; b.u[1] = g ? r1 : k1;
          b.u[2] = g ? k0 : r0; b.u[3] = g ? k1 : r1;
        }

        o0 = MFMA(wA, b.v, o0);
        o1 = MFMA(wB, b.v, o1);
      }
    }

    // ---- store out^T C-frags: 4 consecutive d per reg-quad -> float4 stores ----
#pragma unroll
    for (int dt = 0; dt < 2; ++dt) {
      const f32x16& acc = dt == 0 ? o0 : o1;
      float* po = out + (rb + m) * 64 + dt * 32 + g * 4;
#pragma unroll
      for (int q = 0; q < 4; ++q) {
        float4 s;
        s.x = acc[4*q+0]; s.y = acc[4*q+1]; s.z = acc[4*q+2]; s.w = acc[4*q+3];
        *reinterpret_cast<float4*>(po + 8 * q) = s;  // d = dt*32 + 8q + 4g + 0..3
      }
    }
  }
}

extern "C" void kernel_launch(void* const* d_in, const int* in_sizes, int n_in,
                              void* d_out, int out_size, void* d_ws, size_t ws_size,
                              hipStream_t stream) {
  const float* x  = (const float*)d_in[0];
  const float* w1 = (const float*)d_in[1];
  const float* w2 = (const float*)d_in[2];
  float* out = (float*)d_out;
  ffn_fused<<<dim3(512), dim3(256), 0, stream>>>(x, w1, w2, out);
}

// Round 8
// 86.270 us; speedup vs baseline: 1.8567x; 1.0048x over previous
//
#include <hip/hip_runtime.h>
#include <hip/hip_bf16.h>

typedef __attribute__((ext_vector_type(8))) short short8;
typedef __attribute__((ext_vector_type(16))) float f32x16;

__device__ __forceinline__ unsigned short bfbits(float f) {
  return __builtin_bit_cast(unsigned short, __float2bfloat16(f));
}

__device__ __forceinline__ short8 lds_read16(const short* p, int byteOff) {
  return *reinterpret_cast<const short8*>(reinterpret_cast<const char*>(p) + byteOff);
}

#define MFMA(a, b, c) __builtin_amdgcn_mfma_f32_32x32x16_bf16((a), (b), (c), 0, 0, 0)

__device__ __forceinline__ void load_x8(const float* __restrict__ x, long rb,
                                        int m, int g, float4 raw[8]) {
#pragma unroll
  for (int ks = 0; ks < 4; ++ks) {
    const float* px = x + (rb + m) * 64 + ks * 16 + g * 8;
    raw[2 * ks]     = *reinterpret_cast<const float4*>(px);
    raw[2 * ks + 1] = *reinterpret_cast<const float4*>(px + 4);
  }
}

// Full 32-row tile: convert raw -> bf16 frags, GEMM1 -> relu -> GEMM2, store.
__device__ __forceinline__ void do_tile(const float4 raw[8], const short* w1t,
                                        const short* w2t, float* __restrict__ out,
                                        long rb, int m, int g, int swzm, int swzd) {
  short8 xf[4];
#pragma unroll
  for (int ks = 0; ks < 4; ++ks) {
    const float4 u0 = raw[2 * ks];
    const float4 u1 = raw[2 * ks + 1];
    short8 v;
    v[0] = (short)bfbits(u0.x); v[1] = (short)bfbits(u0.y);
    v[2] = (short)bfbits(u0.z); v[3] = (short)bfbits(u0.w);
    v[4] = (short)bfbits(u1.x); v[5] = (short)bfbits(u1.y);
    v[6] = (short)bfbits(u1.z); v[7] = (short)bfbits(u1.w);
    xf[ks] = v;
  }

  f32x16 o0, o1;  // out^T acc per dt half
#pragma unroll
  for (int i = 0; i < 16; ++i) { o0[i] = 0.f; o1[i] = 0.f; }

#pragma unroll
  for (int ft = 0; ft < 8; ++ft) {
    // GEMM1: h^T tile [32f x 32m] = W1^T frag x x^T frag, K=64 (4 steps)
    short8 a[4];
#pragma unroll
    for (int ks = 0; ks < 4; ++ks)
      a[ks] = lds_read16(w1t, ((ft * 32 + m) * 128 + ks * 32 + g * 16) ^ swzm);

    f32x16 h;
#pragma unroll
    for (int i = 0; i < 16; ++i) h[i] = 0.f;
#pragma unroll
    for (int ks = 0; ks < 4; ++ks) h = MFMA(a[ks], xf[ks], h);

    // relu + pack to bf16 pairs: pk[2q+hh] covers C regs 4q..4q+3
    unsigned pk[8];
#pragma unroll
    for (int q = 0; q < 4; ++q) {
      pk[2*q]   = (unsigned)bfbits(fmaxf(h[4*q+0], 0.f)) | ((unsigned)bfbits(fmaxf(h[4*q+1], 0.f)) << 16);
      pk[2*q+1] = (unsigned)bfbits(fmaxf(h[4*q+2], 0.f)) | ((unsigned)bfbits(fmaxf(h[4*q+3], 0.f)) << 16);
    }

    // GEMM2: out^T += W2^T frag x h^T frag; h^T B-frag built in-register
    // via one cross-half __shfl_xor(32) pair per fragment (PROVEN R1/R3).
#pragma unroll
    for (int sub = 0; sub < 2; ++sub) {
      const int ks2 = 2 * ft + sub;
      const short8 wA = lds_read16(w2t, (m * 512 + ks2 * 32 + g * 16) ^ swzd);
      const short8 wB = lds_read16(w2t, ((32 + m) * 512 + ks2 * 32 + g * 16) ^ swzd);
      const int qa = 2 * sub, qb = 2 * sub + 1;

      union { short8 v; unsigned u[4]; } b;
      {
        unsigned pa0 = pk[2*qa], pa1 = pk[2*qa+1];
        unsigned pb0 = pk[2*qb], pb1 = pk[2*qb+1];
        unsigned s0 = g ? pa0 : pb0, s1 = g ? pa1 : pb1;  // what partner needs
        unsigned k0 = g ? pb0 : pa0, k1 = g ? pb1 : pa1;  // what I keep
        unsigned r0 = __shfl_xor(s0, 32, 64);
        unsigned r1 = __shfl_xor(s1, 32, 64);
        b.u[0] = g ? r0 : k0; b.u[1] = g ? r1 : k1;
        b.u[2] = g ? k0 : r0; b.u[3] = g ? k1 : r1;
      }

      o0 = MFMA(wA, b.v, o0);
      o1 = MFMA(wB, b.v, o1);
    }
  }

  // ---- store out^T C-frags: 4 consecutive d per reg-quad -> float4 stores ----
#pragma unroll
  for (int dt = 0; dt < 2; ++dt) {
    const f32x16& acc = dt == 0 ? o0 : o1;
    float* po = out + (rb + m) * 64 + dt * 32 + g * 4;
#pragma unroll
    for (int q = 0; q < 4; ++q) {
      float4 s;
      s.x = acc[4*q+0]; s.y = acc[4*q+1]; s.z = acc[4*q+2]; s.w = acc[4*q+3];
      *reinterpret_cast<float4*>(po + 8 * q) = s;  // d = dt*32 + 8q + 4g + 0..3
    }
  }
}

// x:[524288][64] f32 (flat reinterpret of [B,E,S,D]; expert = row>>16)
// w1:[8][64][256] f32, w2:[8][256][64] f32, out same shape as x.
// Grid 512 x 256 threads. expert = blockIdx&7 (XCD-pinned), chunk =
// blockIdx>>3 owns 1024 rows; 4 waves x 8 tiles x 32 rows.
//
// R7 measured: staging unroll-2 killed the spill (FETCH 282->67 MB, VGPR 192)
// -> 86.7 us, but latency-bound: Occ 10%, MfmaUtil 12%, BW 1.8-2.3 TB/s.
// R8: depth-2 ping-pong x prefetch (two NAMED buffers, static indexing per
// rule #20) -> 16 outstanding dwordx4/wave, issued ~2 tile-times ahead.
__launch_bounds__(256)
__global__ void ffn_fused(const float* __restrict__ x,
                          const float* __restrict__ w1,
                          const float* __restrict__ w2,
                          float* __restrict__ out) {
  // W1^T: [f=256][d=64] bf16, row pitch 128 B, byte ^= (f&7)<<4
  // W2^T: [d=64][f=256] bf16, row pitch 512 B, byte ^= (d&31)<<4
  __shared__ short w1t[256 * 64];
  __shared__ short w2t[64 * 256];

  const int tid  = threadIdx.x;
  const int lane = tid & 63;
  const int wv   = tid >> 6;   // wave 0..3
  const int m    = lane & 31;
  const int g    = lane >> 5;

  const int e     = blockIdx.x & 7;   // expert -> XCD pinned (128 KB weights/XCD-L2)
  const int chunk = blockIdx.x >> 3;  // 0..63

  const float* W1 = w1 + e * (64 * 256);
  const float* W2 = w2 + e * (256 * 64);

  const long rowBase = (long)e * 65536 + (long)chunk * 1024 + wv * 256;

  // ---- issue tiles 0 and 1 x loads FIRST: latency hides under staging ----
  float4 rawA[8], rawB[8];
  load_x8(x, rowBase + 0,  m, g, rawA);
  load_x8(x, rowBase + 32, m, g, rawB);

  // ---- stage W1^T (thread t owns column f=t; 16 d-quads) ----
  // unroll 2: bound in-flight staging loads (full unroll spilled ~64 dw/thread)
  {
    const int f   = tid;
    const int swz = (f & 7) << 4;
#pragma unroll 2
    for (int i = 0; i < 16; ++i) {
      float a0 = W1[(4 * i + 0) * 256 + f];
      float a1 = W1[(4 * i + 1) * 256 + f];
      float a2 = W1[(4 * i + 2) * 256 + f];
      float a3 = W1[(4 * i + 3) * 256 + f];
      unsigned lo = (unsigned)bfbits(a0) | ((unsigned)bfbits(a1) << 16);
      unsigned hi = (unsigned)bfbits(a2) | ((unsigned)bfbits(a3) << 16);
      const int off = (f * 128 + i * 8) ^ swz;
      *reinterpret_cast<uint2*>(reinterpret_cast<char*>(w1t) + off) = make_uint2(lo, hi);
    }
  }
  // ---- stage W2^T (thread t owns column d=t&63; 16 f-quads) ----
  {
    const int d   = tid & 63;
    const int fb  = tid >> 6;  // 0..3
    const int swz = (d & 31) << 4;
#pragma unroll 2
    for (int i = 0; i < 16; ++i) {
      const int f4 = fb + 4 * i;
      const int f  = 4 * f4;
      float a0 = W2[(f + 0) * 64 + d];
      float a1 = W2[(f + 1) * 64 + d];
      float a2 = W2[(f + 2) * 64 + d];
      float a3 = W2[(f + 3) * 64 + d];
      unsigned lo = (unsigned)bfbits(a0) | ((unsigned)bfbits(a1) << 16);
      unsigned hi = (unsigned)bfbits(a2) | ((unsigned)bfbits(a3) << 16);
      const int off = (d * 512 + f4 * 8) ^ swz;
      *reinterpret_cast<uint2*>(reinterpret_cast<char*>(w2t) + off) = make_uint2(lo, hi);
    }
  }
  __syncthreads();  // only barrier in the kernel

  const int swzm = (m & 7) << 4;
  const int swzd = m << 4;  // ((d&31)<<4, d = m and 32+m give same value)

  // ---- main loop: 8 tiles, ping-pong depth-2 prefetch ----
  for (int it = 0; it < 8; it += 2) {
    const long rb = rowBase + (long)it * 32;

    // tile it (rawA); refill rawA for tile it+2 before compute
    if (it + 2 < 8) {
      // consume rawA into xf happens inside do_tile; but issue the refill
      // AFTER the convert would be ideal -- do_tile converts first thing, so
      // issue refill after a copy of the converted data would cost regs.
      // Instead: convert-before-refill is handled by issuing refill here and
      // relying on vmcnt ordering (rawA's old loads are OLDER than refill;
      // the convert's wait drains only the old ones... NOT true for same
      // registers). Keep it simple and safe: refill after do_tile.
    }
    do_tile(rawA, w1t, w2t, out, rb, m, g, swzm, swzd);
    if (it + 2 < 8) load_x8(x, rowBase + (long)(it + 2) * 32, m, g, rawA);

    // tile it+1 (rawB); its loads have been in flight since it-1 (or prologue)
    do_tile(rawB, w1t, w2t, out, rb + 32, m, g, swzm, swzd);
    if (it + 3 < 8) load_x8(x, rowBase + (long)(it + 3) * 32, m, g, rawB);
  }
}

extern "C" void kernel_launch(void* const* d_in, const int* in_sizes, int n_in,
                              void* d_out, int out_size, void* d_ws, size_t ws_size,
                              hipStream_t stream) {
  const float* x  = (const float*)d_in[0];
  const float* w1 = (const float*)d_in[1];
  const float* w2 = (const float*)d_in[2];
  float* out = (float*)d_out;
  ffn_fused<<<dim3(512), dim3(256), 0, stream>>>(x, w1, w2, out);
}